// Round 4
// baseline (5588.020 us; speedup 1.0000x reference)
//
#include <hip/hip_runtime.h>

#define NN   4096
#define TT   17
#define NTOT (NN*TT)          // 69632
#define NBLK 256
#define NTHR 512
#define KSL  2048             // k-range per block (2 k-blocks)
#define NITMAX 48

// ws layout: int arrv[256*16]; int rel[16]; float part[256*64];
//            then floats r p s x wp0 wp1 [each NTOT]

// low-contention grid barrier: per-block arrival lines + block-0 poller + broadcast release
__device__ __forceinline__ void gbar(int* arrv, int* rel, int ev) {
    __syncthreads();
    if (threadIdx.x == 0) {
        __threadfence();   // release: drain this block's stores
        __hip_atomic_store(&arrv[blockIdx.x * 16], ev, __ATOMIC_RELEASE, __HIP_MEMORY_SCOPE_AGENT);
    }
    if (blockIdx.x == 0) {
        if (threadIdx.x < NBLK) {
            while (__hip_atomic_load(&arrv[threadIdx.x * 16], __ATOMIC_ACQUIRE, __HIP_MEMORY_SCOPE_AGENT) < ev)
                __builtin_amdgcn_s_sleep(2);
        }
        __syncthreads();
        if (threadIdx.x == 0)
            __hip_atomic_store(&rel[0], ev, __ATOMIC_RELEASE, __HIP_MEMORY_SCOPE_AGENT);
    }
    if (threadIdx.x == 0) {
        while (__hip_atomic_load(&rel[0], __ATOMIC_ACQUIRE, __HIP_MEMORY_SCOPE_AGENT) < ev)
            __builtin_amdgcn_s_sleep(2);
        __threadfence();   // acquire: invalidate stale lines for this CU
    }
    __syncthreads();
}

__global__ __launch_bounds__(NTHR, 2)
void gp_cg_kernel(const float* __restrict__ Km, const float* __restrict__ yv,
                  const float* __restrict__ Zm, const float* __restrict__ noise,
                  const int* __restrict__ cg_iters, float* __restrict__ out,
                  float* __restrict__ ws)
{
    const int tid  = threadIdx.x;
    const int b    = blockIdx.x;
    const int lane = tid & 63;
    const int w    = tid >> 6;       // wave 0..7
    const int kb   = b >> 7;         // 0..1  k-block
    const int rb   = b & 127;        // 0..127 row-block

    int*   arrv = (int*)ws;
    int*   rel  = arrv + NBLK*16;
    float* part = (float*)(rel + 16);     // [256][64] padded partial slots
    float* r_   = part + NBLK*64;
    float* p_   = r_  + NTOT;
    float* s_   = p_  + NTOT;
    float* x_   = s_  + NTOT;
    float* wp0  = x_  + NTOT;
    float* wp1  = wp0 + NTOT;

    int ev = 0;

    const float sigma2 = noise[0]*noise[0];
    const int   niters = cg_iters[0];

    __shared__ float rl[TT*KSL];     // 136 KB r-slice, [c][k] layout (conflict-free)
    __shared__ float red[TT], gred[TT];
    __shared__ float al_lds[TT], be_lds[TT], aprev_l[TT], gprev_l[TT];
    __shared__ float scale_l[TT], rhs_l[TT];
    __shared__ float redD[8*40];     // group partials: [g][0..16]=del, [g][20..36]=gam

    // ---- S0+S1: zero state arrays (block-local ranges), per-block ssq partials ----
    for (int i = b*NTHR + tid; i < NTOT; i += NBLK*NTHR) { x_[i]=0.f; p_[i]=0.f; s_[i]=0.f; }
    if (tid < TT) { aprev_l[tid] = 1.f; gprev_l[tid] = 1.f; red[tid] = 0.f; }
    __syncthreads();
    if (tid < 16*TT) {
        int n = b*16 + tid/TT, c = tid % TT;
        float v = (c == 0) ? yv[n] : Zm[n*(TT-1) + (c-1)];
        atomicAdd(&red[c], v*v);          // LDS atomic, block-local
    }
    __syncthreads();
    if (tid < TT) part[b*64 + tid] = red[tid];
    gbar(arrv, rel, ++ev);

    // ---- S2: every block reduces ssq partials, builds scale/rhs, writes r0 ----
    {
        int g = tid >> 6, v = tid & 63;
        if (v < TT) {
            float sm = 0.f;
            #pragma unroll 8
            for (int si = 0; si < 32; ++si) sm += part[(g + 8*si)*64 + v];
            redD[g*40 + v] = sm;
        }
    }
    __syncthreads();
    if (tid < TT) {
        float sc = 0.f;
        #pragma unroll
        for (int g = 0; g < 8; ++g) sc += redD[g*40 + tid];
        float scale, rh;
        if (tid == 0) {
            rh = sqrtf(sc); if (rh < 1e-10f) rh = 1.f;
            scale = 1.f/rh;
        } else {
            float zn = sqrtf(sc);
            float bn = zn/(zn + 1e-10f);
            rh = (bn < 1e-10f) ? 1.f : bn;
            scale = 1.f/((zn + 1e-10f)*rh);
        }
        scale_l[tid] = scale; rhs_l[tid] = rh;
    }
    __syncthreads();
    for (int e = b*NTHR + tid; e < NTOT; e += NBLK*NTHR) {
        int c = e >> 12, n = e & (NN-1);
        float raw = (c == 0) ? yv[n] : Zm[n*(TT-1) + (c-1)];
        r_[e] = raw*scale_l[c];
    }
    gbar(arrv, rel, ++ev);

    const int row0 = rb*32 + w*4;
    const float* Kb = Km + (size_t)row0*NN + kb*KSL;
    float* wpo = (kb == 0) ? wp0 : wp1;

    for (int it = 0; it < niters; ++it) {
        // ================= Phase G: w = K r (partials) + per-block del/gam partials =================
        if (tid < TT) { red[tid] = 0.f; gred[tid] = 0.f; }
        // stage r-slice once, [c][k], consecutive-lane b128 writes
        for (int v = tid; v < TT*(KSL/4); v += NTHR) {
            int c = v >> 9, kq = (v & 511) << 2;
            float4 f = *(const float4*)(r_ + c*NN + kb*KSL + kq);
            *(float4*)(rl + c*KSL + kq) = f;
        }
        __syncthreads();

        float acc[4][TT];
        #pragma unroll
        for (int rr = 0; rr < 4; ++rr)
            #pragma unroll
            for (int c = 0; c < TT; ++c) acc[rr][c] = 0.f;

        float4 kv[4], kvn[4];
        #pragma unroll
        for (int rr = 0; rr < 4; ++rr)
            kv[rr] = *(const float4*)(Kb + rr*NN + 4*lane);

        for (int ch = 0; ch < KSL/256; ++ch) {
            if (ch + 1 < KSL/256) {
                #pragma unroll
                for (int rr = 0; rr < 4; ++rr)
                    kvn[rr] = *(const float4*)(Kb + rr*NN + (ch+1)*256 + 4*lane);
            }
            const float* rlc = rl + ch*256 + 4*lane;
            #pragma unroll
            for (int c = 0; c < TT; ++c) {
                float4 rv = *(const float4*)(rlc + c*KSL);   // conflict-free b128
                #pragma unroll
                for (int rr = 0; rr < 4; ++rr)
                    acc[rr][c] += kv[rr].x*rv.x + kv[rr].y*rv.y + kv[rr].z*rv.z + kv[rr].w*rv.w;
            }
            #pragma unroll
            for (int rr = 0; rr < 4; ++rr) kv[rr] = kvn[rr];
        }

        // 64-lane butterfly reduce over k-split
        #pragma unroll
        for (int rr = 0; rr < 4; ++rr)
            #pragma unroll
            for (int c = 0; c < TT; ++c) {
                float v = acc[rr][c];
                v += __shfl_xor(v, 1, 64);
                v += __shfl_xor(v, 2, 64);
                v += __shfl_xor(v, 4, 64);
                v += __shfl_xor(v, 8, 64);
                v += __shfl_xor(v, 16, 64);
                v += __shfl_xor(v, 32, 64);
                acc[rr][c] = v;
            }

        // epilogue: write wpart, per-block del/gam partials (LDS atomics only)
        if (lane < TT) {
            float dpart = 0.f, gpart = 0.f;
            #pragma unroll
            for (int rr = 0; rr < 4; ++rr) {
                int row = row0 + rr;
                float v = acc[rr][lane];
                wpo[lane*NN + row] = v;
                float rv = r_[lane*NN + row];
                dpart += rv*v;
                gpart += rv*rv;
            }
            atomicAdd(&red[lane], dpart);
            if (kb == 0) atomicAdd(&gred[lane], gpart);
        }
        __syncthreads();
        if (tid < TT) {
            part[b*64 + tid]      = red[tid];                       // del partial
            part[b*64 + 32 + tid] = (kb == 0) ? gred[tid] : 0.f;    // gam partial
        }
        gbar(arrv, rel, ++ev);

        // ================= Phase U: redundant per-block reduce + scalars + updates =================
        {
            int g = tid >> 6, v = tid & 63;
            bool vd = (v < TT), vg = (v >= 32 && v < 32 + TT);
            if (vd || vg) {
                float sm = 0.f;
                #pragma unroll 8
                for (int si = 0; si < 32; ++si) sm += part[(g + 8*si)*64 + v];
                redD[g*40 + (vd ? v : (20 + v - 32))] = sm;
            }
        }
        __syncthreads();
        if (tid < TT) {
            float d = 0.f, gsum = 0.f;
            #pragma unroll
            for (int g = 0; g < 8; ++g) { d += redD[g*40 + tid]; gsum += redD[g*40 + 20 + tid]; }
            float gcur  = gsum;
            float delta = d + sigma2*gcur;          // r^T (K + s2 I) r
            float beta  = 0.f;
            if (it > 0) {
                float gp = gprev_l[tid];
                beta = (fabsf(gp) < 1e-30f) ? 0.f : gcur/gp;
            }
            float ap = aprev_l[tid];
            float D  = delta - ((fabsf(ap) < 1e-30f) ? 0.f : beta*gcur/ap);
            float alpha = (fabsf(D) < 1e-30f) ? 0.f : gcur/D;
            al_lds[tid] = alpha; be_lds[tid] = beta;
            aprev_l[tid] = alpha; gprev_l[tid] = gcur;
        }
        __syncthreads();
        {
            int e = b*NTHR + tid;        // 131072 threads cover NTOT
            if (e < NTOT) {
                int c = e >> 12, n = e & (NN-1);
                float alpha = al_lds[c], beta = be_lds[c];
                float rv = r_[e];
                float wv = wp0[e] + wp1[e] + sigma2*rv;   // full w = A r
                float pv = rv + beta*p_[e];
                float sv = wv + beta*s_[e];
                float xv = x_[e] + alpha*pv;
                float rn = rv - alpha*sv;
                p_[e] = pv; s_[e] = sv; x_[e] = xv; r_[e] = rn;
                if (it == niters - 1) out[n*TT + c] = xv*rhs_l[c];
            }
        }
        gbar(arrv, rel, ++ev);
    }
}

extern "C" void kernel_launch(void* const* d_in, const int* in_sizes, int n_in,
                              void* d_out, int out_size, void* d_ws, size_t ws_size,
                              hipStream_t stream) {
    const float* Km    = (const float*)d_in[0];
    const float* yv    = (const float*)d_in[1];
    const float* Zm    = (const float*)d_in[2];
    const float* noise = (const float*)d_in[3];
    const int*   iters = (const int*)d_in[4];
    float* out = (float*)d_out;
    float* ws  = (float*)d_ws;

    // zero arrival flags + release word (capture-safe async memset)
    hipMemsetAsync(d_ws, 0, (NBLK*16 + 16) * sizeof(int), stream);

    void* args[] = { &Km, &yv, &Zm, &noise, &iters, &out, &ws };
    hipLaunchCooperativeKernel((void*)gp_cg_kernel, dim3(NBLK), dim3(NTHR),
                               args, 0, stream);
}

// Round 5
// 3532.528 us; speedup vs baseline: 1.5819x; 1.5819x over previous
//
#include <hip/hip_runtime.h>

#define NN   4096
#define TT   17
#define PP   16
#define NTOT (NN*TT)          // 69632
#define NIT  47               // reference CG_ITERS (fixed)

// ws float offsets
#define O_PART 0               // [1024][64]: del at +0..16, gam at +32..48
#define O_SC   (1024*64)       // scale[0..16], rhs[32..48]
#define O_ALBE (O_SC + 64)     // alpha[0..16], beta[32..48]
#define O_APGP (O_ALBE + 64)   // aprev[0..16], gprev[32..48]
#define O_R    (O_APGP + 64)
#define O_P    (O_R + NTOT)
#define O_S    (O_P + NTOT)
#define O_X    (O_S + NTOT)
#define O_W0   (O_X + NTOT)    // 4 k-split partials of K@r, each NTOT
// total floats = O_W0 + 4*NTOT = 622784 (~2.5 MB)

// ---- setup: per-column sum of squares of [y | Z] ----
__global__ void k_ssq(const float* __restrict__ y, const float* __restrict__ Z,
                      float* __restrict__ ws) {
    __shared__ float red[TT];
    int t = threadIdx.x;
    if (t < TT) red[t] = 0.f;
    __syncthreads();
    int n = blockIdx.x*256 + t;
    atomicAdd(&red[0], y[n]*y[n]);
    #pragma unroll
    for (int j = 0; j < PP; ++j) { float v = Z[n*PP + j]; atomicAdd(&red[j+1], v*v); }
    __syncthreads();
    if (t < TT) ws[O_PART + blockIdx.x*64 + t] = red[t];
}

// ---- setup: scale / rhs-norm per column ----
__global__ void k_scale(float* __restrict__ ws) {
    int t = threadIdx.x;
    if (t < TT) {
        float s = 0.f;
        #pragma unroll
        for (int i = 0; i < 16; ++i) s += ws[O_PART + i*64 + t];
        float scale, rh;
        if (t == 0) {
            rh = sqrtf(s); if (rh < 1e-10f) rh = 1.f;
            scale = 1.f/rh;
        } else {
            float zn = sqrtf(s);
            float bn = zn/(zn + 1e-10f);
            rh = (bn < 1e-10f) ? 1.f : bn;
            scale = 1.f/((zn + 1e-10f)*rh);
        }
        ws[O_SC + t] = scale; ws[O_SC + 32 + t] = rh;
    }
}

// ---- setup: r0 = b_norm ([c][n] layout), zero p,s,x ----
__global__ void k_init(const float* __restrict__ y, const float* __restrict__ Z,
                       float* __restrict__ ws) {
    int e = blockIdx.x*256 + threadIdx.x;     // 272*256 == NTOT exactly
    int c = e >> 12, n = e & (NN-1);
    float raw = (c == 0) ? y[n] : Z[n*PP + (c-1)];
    ws[O_R + e] = raw * ws[O_SC + c];
    ws[O_P + e] = 0.f; ws[O_S + e] = 0.f; ws[O_X + e] = 0.f;
}

// ---- per-iter: wp_kb = K[rows, kslice] @ r  + per-block del/gam partials ----
__global__ __launch_bounds__(256, 4)
void k_gemm(const float* __restrict__ Km, float* __restrict__ ws) {
    const int t    = threadIdx.x, b = blockIdx.x;
    const int lane = t & 63, w = t >> 6;
    const int rb   = b >> 2, kb = b & 3;      // 256 row-blocks x 4 k-blocks
    const int row0 = rb*16 + w*4;             // 4 rows per wave, 16 per block

    const float* r_ = ws + O_R;
    float* wp = ws + O_W0 + kb*NTOT;

    float acc[4][TT];
    #pragma unroll
    for (int rr = 0; rr < 4; ++rr)
        #pragma unroll
        for (int c = 0; c < TT; ++c) acc[rr][c] = 0.f;

    const float* Kb = Km + (size_t)row0*NN + kb*1024 + 2*lane;
    const float* rbase = r_ + kb*1024 + 2*lane;

    float2 kv[4], kvn[4];
    #pragma unroll
    for (int rr = 0; rr < 4; ++rr) kv[rr] = *(const float2*)(Kb + rr*NN);

    for (int ch = 0; ch < 8; ++ch) {          // 8 chunks x 128 k
        if (ch < 7) {
            #pragma unroll
            for (int rr = 0; rr < 4; ++rr)
                kvn[rr] = *(const float2*)(Kb + rr*NN + (ch+1)*128);
        }
        const float* rp = rbase + ch*128;
        #pragma unroll
        for (int c = 0; c < TT; ++c) {
            float2 rv = *(const float2*)rp;
            rp += NN;
            #pragma unroll
            for (int rr = 0; rr < 4; ++rr)
                acc[rr][c] += kv[rr].x*rv.x + kv[rr].y*rv.y;
        }
        #pragma unroll
        for (int rr = 0; rr < 4; ++rr) kv[rr] = kvn[rr];
    }

    // butterfly-reduce the 64-way k split
    #pragma unroll
    for (int rr = 0; rr < 4; ++rr)
        #pragma unroll
        for (int c = 0; c < TT; ++c) {
            float v = acc[rr][c];
            v += __shfl_xor(v, 1, 64);
            v += __shfl_xor(v, 2, 64);
            v += __shfl_xor(v, 4, 64);
            v += __shfl_xor(v, 8, 64);
            v += __shfl_xor(v, 16, 64);
            v += __shfl_xor(v, 32, 64);
            acc[rr][c] = v;
        }

    // CONSTANT-indexed select (no dynamic reg indexing -> no scratch):
    // lane c keeps column c's four row-sums in vout[0..3]
    float vout[4] = {0.f, 0.f, 0.f, 0.f};
    #pragma unroll
    for (int c = 0; c < TT; ++c) {
        bool m = (lane == c);
        #pragma unroll
        for (int rr = 0; rr < 4; ++rr)
            vout[rr] = m ? acc[rr][c] : vout[rr];
    }

    __shared__ float redd[TT], redg[TT];
    if (t < TT) { redd[t] = 0.f; redg[t] = 0.f; }
    __syncthreads();
    if (lane < TT) {
        float dp = 0.f, gp = 0.f;
        #pragma unroll
        for (int rr = 0; rr < 4; ++rr) {
            int row = row0 + rr;
            float v = vout[rr];
            wp[lane*NN + row] = v;
            float rv = r_[lane*NN + row];
            dp += rv*v;
            gp += rv*rv;
        }
        atomicAdd(&redd[lane], dp);
        if (kb == 0) atomicAdd(&redg[lane], gp);
    }
    __syncthreads();
    if (t < TT) {
        ws[O_PART + b*64 + t]      = redd[t];
        ws[O_PART + b*64 + 32 + t] = (kb == 0) ? redg[t] : 0.f;
    }
}

// ---- per-iter: reduce 1024 partial slots, compute alpha/beta (pipelined CG) ----
__global__ void k_red(const float* __restrict__ noise, float* __restrict__ ws, int it) {
    __shared__ float sm[8][64];
    int t = threadIdx.x, seg = t >> 6, j = t & 63;   // 512 threads, 8 segments
    float s = 0.f;
    if (j < TT || (j >= 32 && j < 32 + TT)) {
        for (int i = 0; i < 128; ++i)
            s += ws[O_PART + (seg*128 + i)*64 + j];
    }
    sm[seg][j] = s;
    __syncthreads();
    if (t < TT) {
        float del = 0.f, gam = 0.f;
        #pragma unroll
        for (int g = 0; g < 8; ++g) { del += sm[g][t]; gam += sm[g][32 + t]; }
        float s2 = noise[0]*noise[0];
        float delta = del + s2*gam;               // r^T (K + s2 I) r
        float beta = 0.f, D = delta;
        if (it > 0) {
            float gp = ws[O_APGP + 32 + t];
            beta = (fabsf(gp) < 1e-30f) ? 0.f : gam/gp;
            float ap = ws[O_APGP + t];
            D = delta - ((fabsf(ap) < 1e-30f) ? 0.f : beta*gam/ap);
        }
        float alpha = (fabsf(D) < 1e-30f) ? 0.f : gam/D;
        ws[O_ALBE + t] = alpha; ws[O_ALBE + 32 + t] = beta;
        ws[O_APGP + t] = alpha; ws[O_APGP + 32 + t] = gam;
    }
}

// ---- per-iter: element-wise p,s,x,r updates (fully coalesced, [c][n] linear) ----
__global__ void k_upd(const float* __restrict__ noise, float* __restrict__ ws,
                      float* __restrict__ out, int last) {
    int e = blockIdx.x*256 + threadIdx.x;     // 272*256 == NTOT
    int c = e >> 12, n = e & (NN-1);
    float s2 = noise[0]*noise[0];
    float al = ws[O_ALBE + c], be = ws[O_ALBE + 32 + c];
    float rv = ws[O_R + e];
    float wv = ws[O_W0 + e] + ws[O_W0 + NTOT + e]
             + ws[O_W0 + 2*NTOT + e] + ws[O_W0 + 3*NTOT + e] + s2*rv;
    float pn = rv + be*ws[O_P + e];
    float sn = wv + be*ws[O_S + e];
    float xn = ws[O_X + e] + al*pn;
    float rn = rv - al*sn;
    ws[O_P + e] = pn; ws[O_S + e] = sn; ws[O_X + e] = xn; ws[O_R + e] = rn;
    if (last) out[n*TT + c] = xn * ws[O_SC + 32 + c];
}

extern "C" void kernel_launch(void* const* d_in, const int* in_sizes, int n_in,
                              void* d_out, int out_size, void* d_ws, size_t ws_size,
                              hipStream_t stream) {
    const float* Km    = (const float*)d_in[0];
    const float* yv    = (const float*)d_in[1];
    const float* Zm    = (const float*)d_in[2];
    const float* noise = (const float*)d_in[3];
    float* out = (float*)d_out;
    float* ws  = (float*)d_ws;

    k_ssq  <<<16, 256, 0, stream>>>(yv, Zm, ws);
    k_scale<<<1,   64, 0, stream>>>(ws);
    k_init <<<272, 256, 0, stream>>>(yv, Zm, ws);
    for (int it = 0; it < NIT; ++it) {
        k_gemm<<<1024, 256, 0, stream>>>(Km, ws);
        k_red <<<1,    512, 0, stream>>>(noise, ws, it);
        k_upd <<<272,  256, 0, stream>>>(noise, ws, out, it == NIT-1);
    }
}

// Round 6
// 2315.384 us; speedup vs baseline: 2.4134x; 1.5257x over previous
//
#include <hip/hip_runtime.h>

#define NN   4096
#define TT   17
#define PP   16
#define NTOT (NN*TT)          // 69632
#define NIT  47               // reference CG_ITERS (fixed)
#define KSL  1024             // k-slice per block (4 k-blocks)

// ws float offsets
#define O_PART 0               // [1024][64]: del at +0..16, gam at +32..48
#define O_SC   (1024*64)       // scale[0..16], rhs[32..48]
#define O_ALBE (O_SC + 64)     // alpha[0..16], beta[32..48]
#define O_APGP (O_ALBE + 64)   // aprev[0..16], gprev[32..48]
#define O_R    (O_APGP + 64)
#define O_P    (O_R + NTOT)
#define O_S    (O_P + NTOT)
#define O_X    (O_S + NTOT)
#define O_W0   (O_X + NTOT)    // 4 k-split partials of K@r, each NTOT

// ---- setup: per-column sum of squares of [y | Z] ----
__global__ void k_ssq(const float* __restrict__ y, const float* __restrict__ Z,
                      float* __restrict__ ws) {
    __shared__ float red[TT];
    int t = threadIdx.x;
    if (t < TT) red[t] = 0.f;
    __syncthreads();
    int n = blockIdx.x*256 + t;
    atomicAdd(&red[0], y[n]*y[n]);
    #pragma unroll
    for (int j = 0; j < PP; ++j) { float v = Z[n*PP + j]; atomicAdd(&red[j+1], v*v); }
    __syncthreads();
    if (t < TT) ws[O_PART + blockIdx.x*64 + t] = red[t];
}

// ---- setup: scale / rhs-norm per column ----
__global__ void k_scale(float* __restrict__ ws) {
    int t = threadIdx.x;
    if (t < TT) {
        float s = 0.f;
        #pragma unroll
        for (int i = 0; i < 16; ++i) s += ws[O_PART + i*64 + t];
        float scale, rh;
        if (t == 0) {
            rh = sqrtf(s); if (rh < 1e-10f) rh = 1.f;
            scale = 1.f/rh;
        } else {
            float zn = sqrtf(s);
            float bn = zn/(zn + 1e-10f);
            rh = (bn < 1e-10f) ? 1.f : bn;
            scale = 1.f/((zn + 1e-10f)*rh);
        }
        ws[O_SC + t] = scale; ws[O_SC + 32 + t] = rh;
    }
}

// ---- setup: r0 = b_norm ([c][n] layout), zero p,s,x ----
__global__ void k_init(const float* __restrict__ y, const float* __restrict__ Z,
                       float* __restrict__ ws) {
    int e = blockIdx.x*256 + threadIdx.x;     // 272*256 == NTOT exactly
    int c = e >> 12, n = e & (NN-1);
    float raw = (c == 0) ? y[n] : Z[n*PP + (c-1)];
    ws[O_R + e] = raw * ws[O_SC + c];
    ws[O_P + e] = 0.f; ws[O_S + e] = 0.f; ws[O_X + e] = 0.f;
}

// ---- per-iter GEMM: wp_kb = K[rows, kslice] @ r + per-block del/gam partials ----
// LDS-staged r (68 KB -> 2 blocks/CU -> 2 waves/SIMD -> 256-VGPR budget),
// K streamed as float4 with 2-chunk register prefetch issued before staging.
__global__ __launch_bounds__(256, 2)
void k_gemm(const float* __restrict__ Km, float* __restrict__ ws) {
    const int t    = threadIdx.x, b = blockIdx.x;
    const int lane = t & 63, w = t >> 6;
    const int rb   = b >> 2, kb = b & 3;      // 256 row-blocks x 4 k-blocks
    const int row0 = rb*16 + w*4;             // 4 rows per wave

    const float* r_ = ws + O_R;
    float* wp = ws + O_W0 + kb*NTOT;

    __shared__ float rl[TT*KSL];              // [c][k], 68 KB, conflict-free b128
    __shared__ float redd[TT], redg[TT];

    // issue K prefetch for chunks 0 and 1 FIRST (overlaps the staging loads)
    const float* Kb = Km + (size_t)row0*NN + kb*KSL + 4*lane;
    float4 kv[4], kvn[4];
    #pragma unroll
    for (int rr = 0; rr < 4; ++rr) kv[rr]  = *(const float4*)(Kb + rr*NN);
    #pragma unroll
    for (int rr = 0; rr < 4; ++rr) kvn[rr] = *(const float4*)(Kb + rr*NN + 256);

    // stage r slice to LDS (17 coalesced float4 bursts per thread)
    for (int v = t; v < TT*(KSL/4); v += 256) {
        int c = v >> 8, kq = (v & 255) << 2;
        float4 f = *(const float4*)(r_ + c*NN + kb*KSL + kq);
        *(float4*)(rl + c*KSL + kq) = f;
    }
    if (t < TT) { redd[t] = 0.f; redg[t] = 0.f; }
    __syncthreads();

    float acc[4][TT];
    #pragma unroll
    for (int rr = 0; rr < 4; ++rr)
        #pragma unroll
        for (int c = 0; c < TT; ++c) acc[rr][c] = 0.f;

    for (int ch = 0; ch < 4; ++ch) {          // 4 chunks x 256 k (float4/lane)
        float4 kvt[4];
        if (ch + 2 < 4) {
            #pragma unroll
            for (int rr = 0; rr < 4; ++rr)
                kvt[rr] = *(const float4*)(Kb + rr*NN + (ch+2)*256);
        }
        const float* rlc = rl + ch*256 + 4*lane;
        #pragma unroll
        for (int c = 0; c < TT; ++c) {
            float4 rv = *(const float4*)(rlc + c*KSL);
            #pragma unroll
            for (int rr = 0; rr < 4; ++rr)
                acc[rr][c] += kv[rr].x*rv.x + kv[rr].y*rv.y + kv[rr].z*rv.z + kv[rr].w*rv.w;
        }
        #pragma unroll
        for (int rr = 0; rr < 4; ++rr) { kv[rr] = kvn[rr]; kvn[rr] = kvt[rr]; }
    }

    // butterfly-reduce the 64-way k split
    #pragma unroll
    for (int rr = 0; rr < 4; ++rr)
        #pragma unroll
        for (int c = 0; c < TT; ++c) {
            float v = acc[rr][c];
            v += __shfl_xor(v, 1, 64);
            v += __shfl_xor(v, 2, 64);
            v += __shfl_xor(v, 4, 64);
            v += __shfl_xor(v, 8, 64);
            v += __shfl_xor(v, 16, 64);
            v += __shfl_xor(v, 32, 64);
            acc[rr][c] = v;
        }

    // constant-indexed select: lane c keeps column c's four row-sums
    float vout[4] = {0.f, 0.f, 0.f, 0.f};
    #pragma unroll
    for (int c = 0; c < TT; ++c) {
        bool m = (lane == c);
        #pragma unroll
        for (int rr = 0; rr < 4; ++rr)
            vout[rr] = m ? acc[rr][c] : vout[rr];
    }

    if (lane < TT) {
        float dp = 0.f, gp = 0.f;
        #pragma unroll
        for (int rr = 0; rr < 4; ++rr) {
            int row = row0 + rr;
            float v = vout[rr];
            wp[lane*NN + row] = v;
            float rv = r_[lane*NN + row];
            dp += rv*v;
            gp += rv*rv;
        }
        atomicAdd(&redd[lane], dp);
        if (kb == 0) atomicAdd(&redg[lane], gp);
    }
    __syncthreads();
    if (t < TT) {
        ws[O_PART + b*64 + t]      = redd[t];
        ws[O_PART + b*64 + 32 + t] = (kb == 0) ? redg[t] : 0.f;
    }
}

// ---- per-iter: reduce 1024 partial slots, compute alpha/beta (pipelined CG) ----
__global__ void k_red(const float* __restrict__ noise, float* __restrict__ ws, int it) {
    __shared__ float sm[8][64];
    int t = threadIdx.x, seg = t >> 6, j = t & 63;   // 512 threads, 8 segments
    float s = 0.f;
    if (j < TT || (j >= 32 && j < 32 + TT)) {
        for (int i = 0; i < 128; ++i)
            s += ws[O_PART + (seg*128 + i)*64 + j];
    }
    sm[seg][j] = s;
    __syncthreads();
    if (t < TT) {
        float del = 0.f, gam = 0.f;
        #pragma unroll
        for (int g = 0; g < 8; ++g) { del += sm[g][t]; gam += sm[g][32 + t]; }
        float s2 = noise[0]*noise[0];
        float delta = del + s2*gam;               // r^T (K + s2 I) r
        float beta = 0.f, D = delta;
        if (it > 0) {
            float gp = ws[O_APGP + 32 + t];
            beta = (fabsf(gp) < 1e-30f) ? 0.f : gam/gp;
            float ap = ws[O_APGP + t];
            D = delta - ((fabsf(ap) < 1e-30f) ? 0.f : beta*gam/ap);
        }
        float alpha = (fabsf(D) < 1e-30f) ? 0.f : gam/D;
        ws[O_ALBE + t] = alpha; ws[O_ALBE + 32 + t] = beta;
        ws[O_APGP + t] = alpha; ws[O_APGP + 32 + t] = gam;
    }
}

// ---- per-iter: element-wise p,s,x,r updates (fully coalesced, [c][n] linear) ----
__global__ void k_upd(const float* __restrict__ noise, float* __restrict__ ws,
                      float* __restrict__ out, int last) {
    int e = blockIdx.x*256 + threadIdx.x;     // 272*256 == NTOT
    int c = e >> 12, n = e & (NN-1);
    float s2 = noise[0]*noise[0];
    float al = ws[O_ALBE + c], be = ws[O_ALBE + 32 + c];
    float rv = ws[O_R + e];
    float wv = ws[O_W0 + e] + ws[O_W0 + NTOT + e]
             + ws[O_W0 + 2*NTOT + e] + ws[O_W0 + 3*NTOT + e] + s2*rv;
    float pn = rv + be*ws[O_P + e];
    float sn = wv + be*ws[O_S + e];
    float xn = ws[O_X + e] + al*pn;
    float rn = rv - al*sn;
    ws[O_P + e] = pn; ws[O_S + e] = sn; ws[O_X + e] = xn; ws[O_R + e] = rn;
    if (last) out[n*TT + c] = xn * ws[O_SC + 32 + c];
}

extern "C" void kernel_launch(void* const* d_in, const int* in_sizes, int n_in,
                              void* d_out, int out_size, void* d_ws, size_t ws_size,
                              hipStream_t stream) {
    const float* Km    = (const float*)d_in[0];
    const float* yv    = (const float*)d_in[1];
    const float* Zm    = (const float*)d_in[2];
    const float* noise = (const float*)d_in[3];
    float* out = (float*)d_out;
    float* ws  = (float*)d_ws;

    k_ssq  <<<16, 256, 0, stream>>>(yv, Zm, ws);
    k_scale<<<1,   64, 0, stream>>>(ws);
    k_init <<<272, 256, 0, stream>>>(yv, Zm, ws);
    for (int it = 0; it < NIT; ++it) {
        k_gemm<<<1024, 256, 0, stream>>>(Km, ws);
        k_red <<<1,    512, 0, stream>>>(noise, ws, it);
        k_upd <<<272,  256, 0, stream>>>(noise, ws, out, it == NIT-1);
    }
}

// Round 7
// 2001.146 us; speedup vs baseline: 2.7924x; 1.1570x over previous
//
#include <hip/hip_runtime.h>

#define NN   4096
#define TT   17
#define PP   16
#define NTOT (NN*TT)          // 69632
#define NIT  47               // reference CG_ITERS (fixed)
#define KSL  1024             // k-slice per block (4 k-blocks)

// ws float offsets
#define O_PART 0               // [512][64]: del at +0..16, gam at +32..48
#define O_SC   (1024*64)       // scale[0..16], rhs[32..48]
#define O_ALBE (O_SC + 64)     // alpha[0..16], beta[32..48]
#define O_APGP (O_ALBE + 64)   // aprev[0..16], gprev[32..48]
#define O_R    (O_APGP + 64)
#define O_P    (O_R + NTOT)
#define O_S    (O_P + NTOT)
#define O_X    (O_S + NTOT)
#define O_W0   (O_X + NTOT)    // 4 k-split partials of K@r, each NTOT

// ---- setup: per-column sum of squares of [y | Z] ----
__global__ void k_ssq(const float* __restrict__ y, const float* __restrict__ Z,
                      float* __restrict__ ws) {
    __shared__ float red[TT];
    int t = threadIdx.x;
    if (t < TT) red[t] = 0.f;
    __syncthreads();
    int n = blockIdx.x*256 + t;
    atomicAdd(&red[0], y[n]*y[n]);
    #pragma unroll
    for (int j = 0; j < PP; ++j) { float v = Z[n*PP + j]; atomicAdd(&red[j+1], v*v); }
    __syncthreads();
    if (t < TT) ws[O_PART + blockIdx.x*64 + t] = red[t];
}

// ---- setup: scale / rhs-norm per column ----
__global__ void k_scale(float* __restrict__ ws) {
    int t = threadIdx.x;
    if (t < TT) {
        float s = 0.f;
        #pragma unroll
        for (int i = 0; i < 16; ++i) s += ws[O_PART + i*64 + t];
        float scale, rh;
        if (t == 0) {
            rh = sqrtf(s); if (rh < 1e-10f) rh = 1.f;
            scale = 1.f/rh;
        } else {
            float zn = sqrtf(s);
            float bn = zn/(zn + 1e-10f);
            rh = (bn < 1e-10f) ? 1.f : bn;
            scale = 1.f/((zn + 1e-10f)*rh);
        }
        ws[O_SC + t] = scale; ws[O_SC + 32 + t] = rh;
    }
}

// ---- setup: r0 = b_norm ([c][n] layout), zero p,s,x ----
__global__ void k_init(const float* __restrict__ y, const float* __restrict__ Z,
                       float* __restrict__ ws) {
    int e = blockIdx.x*256 + threadIdx.x;     // 272*256 == NTOT exactly
    int c = e >> 12, n = e & (NN-1);
    float raw = (c == 0) ? y[n] : Z[n*PP + (c-1)];
    ws[O_R + e] = raw * ws[O_SC + c];
    ws[O_P + e] = 0.f; ws[O_S + e] = 0.f; ws[O_X + e] = 0.f;
}

// ---- per-iter GEMM: 512 threads, 32 rows/block, 68 KB LDS -> 2 blocks/CU
//      = 16 waves/CU (50% occ). 2-stage butterfly + LDS-transpose finish. ----
__global__ __launch_bounds__(512, 4)
void k_gemm(const float* __restrict__ Km, float* __restrict__ ws) {
    const int t    = threadIdx.x, b = blockIdx.x;
    const int lane = t & 63, w = t >> 6;      // 8 waves
    const int rb   = b >> 2, kb = b & 3;      // 128 row-blocks x 4 k-blocks
    const int row0 = rb*32 + w*4;             // 4 rows per wave

    const float* r_ = ws + O_R;
    float* wp = ws + O_W0 + kb*NTOT;

    __shared__ float rl[TT*KSL];              // [c][k], 68 KB; reused for reduce
    __shared__ float redd[TT], redg[TT];

    // K prefetch for chunks 0,1 first (overlaps staging)
    const float* Kb = Km + (size_t)row0*NN + kb*KSL + 4*lane;
    float4 kv[4], kvn[4];
    #pragma unroll
    for (int rr = 0; rr < 4; ++rr) kv[rr]  = *(const float4*)(Kb + rr*NN);
    #pragma unroll
    for (int rr = 0; rr < 4; ++rr) kvn[rr] = *(const float4*)(Kb + rr*NN + 256);

    if (t < TT) { redd[t] = 0.f; redg[t] = 0.f; }
    // stage r slice to LDS (coalesced float4)
    for (int v = t; v < TT*(KSL/4); v += 512) {
        int c = v >> 8, kq = (v & 255) << 2;
        *(float4*)(rl + c*KSL + kq) = *(const float4*)(r_ + c*NN + kb*KSL + kq);
    }
    __syncthreads();

    float acc[4][TT];
    #pragma unroll
    for (int rr = 0; rr < 4; ++rr)
        #pragma unroll
        for (int c = 0; c < TT; ++c) acc[rr][c] = 0.f;

    for (int ch = 0; ch < 4; ++ch) {          // 4 chunks x 256 k
        float4 kvt[4];
        if (ch + 2 < 4) {
            #pragma unroll
            for (int rr = 0; rr < 4; ++rr)
                kvt[rr] = *(const float4*)(Kb + rr*NN + (ch+2)*256);
        }
        const float* rlc = rl + ch*256 + 4*lane;
        #pragma unroll
        for (int c = 0; c < TT; ++c) {
            float4 rv = *(const float4*)(rlc + c*KSL);
            #pragma unroll
            for (int rr = 0; rr < 4; ++rr)
                acc[rr][c] += kv[rr].x*rv.x + kv[rr].y*rv.y + kv[rr].z*rv.z + kv[rr].w*rv.w;
        }
        #pragma unroll
        for (int rr = 0; rr < 4; ++rr) { kv[rr] = kvn[rr]; kvn[rr] = kvt[rr]; }
    }

    // partial butterfly: 64 -> 16 lane-classes (2 stages instead of 6)
    #pragma unroll
    for (int rr = 0; rr < 4; ++rr)
        #pragma unroll
        for (int c = 0; c < TT; ++c) {
            float v = acc[rr][c];
            v += __shfl_xor(v, 32, 64);
            v += __shfl_xor(v, 16, 64);
            acc[rr][c] = v;
        }

    __syncthreads();                          // all waves done reading rl
    float4* part2 = (float4*)rl;              // reuse: [w][c][16] float4(rr)
    if (lane < 16) {
        #pragma unroll
        for (int c = 0; c < TT; ++c)
            part2[(w*TT + c)*16 + lane] =
                make_float4(acc[0][c], acc[1][c], acc[2][c], acc[3][c]);
    }
    __syncthreads();

    if (t < 8*TT) {                           // 136 finish threads
        int w2 = t / TT, c2 = t % TT;
        float4 s = make_float4(0.f, 0.f, 0.f, 0.f);
        #pragma unroll
        for (int i = 0; i < 16; ++i) {
            float4 u = part2[(w2*TT + c2)*16 + i];
            s.x += u.x; s.y += u.y; s.z += u.z; s.w += u.w;
        }
        int row = rb*32 + w2*4;
        *(float4*)(wp + c2*NN + row) = s;     // dwordx4 partial write
        float4 rv = *(const float4*)(r_ + c2*NN + row);
        float dp = rv.x*s.x + rv.y*s.y + rv.z*s.z + rv.w*s.w;
        float gp = rv.x*rv.x + rv.y*rv.y + rv.z*rv.z + rv.w*rv.w;
        atomicAdd(&redd[c2], dp);
        if (kb == 0) atomicAdd(&redg[c2], gp);
    }
    __syncthreads();
    if (t < TT) {
        ws[O_PART + b*64 + t]      = redd[t];
        ws[O_PART + b*64 + 32 + t] = (kb == 0) ? redg[t] : 0.f;
    }
}

// ---- per-iter: reduce 512 partial slots, compute alpha/beta (pipelined CG) ----
__global__ void k_red(const float* __restrict__ noise, float* __restrict__ ws, int it) {
    __shared__ float sm[8][64];
    int t = threadIdx.x, seg = t >> 6, j = t & 63;   // 512 threads, 8 segments
    float s = 0.f;
    if (j < TT || (j >= 32 && j < 32 + TT)) {
        for (int i = 0; i < 64; ++i)
            s += ws[O_PART + (seg*64 + i)*64 + j];
    }
    sm[seg][j] = s;
    __syncthreads();
    if (t < TT) {
        float del = 0.f, gam = 0.f;
        #pragma unroll
        for (int g = 0; g < 8; ++g) { del += sm[g][t]; gam += sm[g][32 + t]; }
        float s2 = noise[0]*noise[0];
        float delta = del + s2*gam;               // r^T (K + s2 I) r
        float beta = 0.f, D = delta;
        if (it > 0) {
            float gp = ws[O_APGP + 32 + t];
            beta = (fabsf(gp) < 1e-30f) ? 0.f : gam/gp;
            float ap = ws[O_APGP + t];
            D = delta - ((fabsf(ap) < 1e-30f) ? 0.f : beta*gam/ap);
        }
        float alpha = (fabsf(D) < 1e-30f) ? 0.f : gam/D;
        ws[O_ALBE + t] = alpha; ws[O_ALBE + 32 + t] = beta;
        ws[O_APGP + t] = alpha; ws[O_APGP + 32 + t] = gam;
    }
}

// ---- per-iter: element-wise p,s,x,r updates (fully coalesced, [c][n] linear) ----
__global__ void k_upd(const float* __restrict__ noise, float* __restrict__ ws,
                      float* __restrict__ out, int last) {
    int e = blockIdx.x*256 + threadIdx.x;     // 272*256 == NTOT
    int c = e >> 12, n = e & (NN-1);
    float s2 = noise[0]*noise[0];
    float al = ws[O_ALBE + c], be = ws[O_ALBE + 32 + c];
    float rv = ws[O_R + e];
    float wv = ws[O_W0 + e] + ws[O_W0 + NTOT + e]
             + ws[O_W0 + 2*NTOT + e] + ws[O_W0 + 3*NTOT + e] + s2*rv;
    float pn = rv + be*ws[O_P + e];
    float sn = wv + be*ws[O_S + e];
    float xn = ws[O_X + e] + al*pn;
    float rn = rv - al*sn;
    ws[O_P + e] = pn; ws[O_S + e] = sn; ws[O_X + e] = xn; ws[O_R + e] = rn;
    if (last) out[n*TT + c] = xn * ws[O_SC + 32 + c];
}

extern "C" void kernel_launch(void* const* d_in, const int* in_sizes, int n_in,
                              void* d_out, int out_size, void* d_ws, size_t ws_size,
                              hipStream_t stream) {
    const float* Km    = (const float*)d_in[0];
    const float* yv    = (const float*)d_in[1];
    const float* Zm    = (const float*)d_in[2];
    const float* noise = (const float*)d_in[3];
    float* out = (float*)d_out;
    float* ws  = (float*)d_ws;

    k_ssq  <<<16, 256, 0, stream>>>(yv, Zm, ws);
    k_scale<<<1,   64, 0, stream>>>(ws);
    k_init <<<272, 256, 0, stream>>>(yv, Zm, ws);
    for (int it = 0; it < NIT; ++it) {
        k_gemm<<<512, 512, 0, stream>>>(Km, ws);
        k_red <<<1,   512, 0, stream>>>(noise, ws, it);
        k_upd <<<272, 256, 0, stream>>>(noise, ws, out, it == NIT-1);
    }
}